// Round 5
// baseline (561.922 us; speedup 1.0000x reference)
//
#include <hip/hip_runtime.h>

// ---------------------------------------------------------------------------
// BlockGNN on MI355X, round 7:
//   - GEMM rewritten as LDS-free direct-global MFMA: fragments loaded straight
//     from L1/L2 (B is 128KB L2-resident; A rows contiguous). No barriers,
//     fully unrolled k-loop, 782 blocks of 256 thr. Round-6 GEMM had 16
//     syncthreads/block at 1.5 blocks/CU => ~50us/layer hidden cost.
//   - aggregate: unchanged (proven at the 8xXCD L2-duplication floor:
//     FETCH 186MB ~= 8 x 25.6MB working set; 3.7 TB/s across 3 variants).
// ---------------------------------------------------------------------------

typedef __bf16 bf16x8 __attribute__((ext_vector_type(8)));
typedef float f32x4 __attribute__((ext_vector_type(4)));
typedef unsigned int u32x4 __attribute__((ext_vector_type(4)));

__device__ inline float bf2f(unsigned short u) {
  union { unsigned int i; float f; } v;
  v.i = (unsigned int)u << 16;
  return v.f;
}
__device__ inline unsigned short f2bf(float f) {
  union { unsigned int i; float f; } v;
  v.f = f;
  unsigned int i = v.i;
  return (unsigned short)((i + 0x7fffu + ((i >> 16) & 1u)) >> 16);  // RNE
}
__device__ inline unsigned int pack2(float a, float b) {
  return (unsigned int)f2bf(a) | ((unsigned int)f2bf(b) << 16);
}
__device__ inline void acc8(float* acc, uint4 r) {
  unsigned int w[4] = {r.x, r.y, r.z, r.w};
#pragma unroll
  for (int q = 0; q < 4; ++q) {
    acc[2 * q] += bf2f((unsigned short)(w[q] & 0xffffu));
    acc[2 * q + 1] += bf2f((unsigned short)(w[q] >> 16));
  }
}
// masked accumulate of a u32x4 (4x2 bf16); msk==0 squashes to +0.0
__device__ inline void acc8m(float* acc, u32x4 r, unsigned msk) {
#pragma unroll
  for (int q = 0; q < 4; ++q) {
    unsigned w = r[q] & msk;
    acc[2 * q] += bf2f((unsigned short)(w & 0xffffu));
    acc[2 * q + 1] += bf2f((unsigned short)(w >> 16));
  }
}

// ----------------------------- CSR build -----------------------------------

__global__ void count_deg_kernel(const int* __restrict__ dst, int* __restrict__ deg, int E) {
  int e = blockIdx.x * blockDim.x + threadIdx.x;
  if (e < E) atomicAdd(&deg[dst[e]], 1);
}

// fused: per-block degree sums for the scan + inv_s = rsqrt(deg+1)
__global__ void scan_partial_kernel(const int* __restrict__ deg, float* __restrict__ inv_s,
                                    int* __restrict__ bsum, int N) {
  __shared__ int s[256];
  int i = blockIdx.x * 256 + threadIdx.x;
  int d = (i < N) ? deg[i] : 0;
  if (i < N) inv_s[i] = rsqrtf((float)(d + 1));  // +1 self loop
  s[threadIdx.x] = d;
  __syncthreads();
  for (int off = 128; off > 0; off >>= 1) {
    if (threadIdx.x < off) s[threadIdx.x] += s[threadIdx.x + off];
    __syncthreads();
  }
  if (threadIdx.x == 0) bsum[blockIdx.x] = s[0];
}

__global__ void scan_block_kernel(const int* __restrict__ bsum, int* __restrict__ boff,
                                  int* __restrict__ row_off, int NB, int N) {
  __shared__ int s[256];
  int v = (threadIdx.x < NB) ? bsum[threadIdx.x] : 0;
  s[threadIdx.x] = v;
  __syncthreads();
  for (int off = 1; off < 256; off <<= 1) {
    int t = (threadIdx.x >= off) ? s[threadIdx.x - off] : 0;
    __syncthreads();
    s[threadIdx.x] += t;
    __syncthreads();
  }
  boff[threadIdx.x] = s[threadIdx.x] - v;
  if (threadIdx.x == 255) row_off[N] = s[255];
}

__global__ void scan_final_kernel(const int* __restrict__ deg, const int* __restrict__ boff,
                                  int* __restrict__ row_off, int N) {
  __shared__ int s[256];
  int i = blockIdx.x * 256 + threadIdx.x;
  int v = (i < N) ? deg[i] : 0;
  s[threadIdx.x] = v;
  __syncthreads();
  for (int off = 1; off < 256; off <<= 1) {
    int t = (threadIdx.x >= off) ? s[threadIdx.x - off] : 0;
    __syncthreads();
    s[threadIdx.x] += t;
    __syncthreads();
  }
  if (i < N) row_off[i] = boff[blockIdx.x] + s[threadIdx.x] - v;
}

__global__ void fill_csr_kernel(const int* __restrict__ src, const int* __restrict__ dst,
                                const int* __restrict__ row_off, int* __restrict__ cursor,
                                int* __restrict__ col, int E) {
  int e = blockIdx.x * blockDim.x + threadIdx.x;
  if (e < E) {
    int d = dst[e];
    int pos = atomicAdd(&cursor[d], 1);
    col[row_off[d] + pos] = src[e];
  }
}

// ----------------------------- prep ----------------------------------------

// u_x[i][c] = bf16( inv_s[i] * x[i][c] ),  CH = 128
__global__ void prep_ux_kernel(const float* __restrict__ x, const float* __restrict__ inv_s,
                               unsigned short* __restrict__ u, int total) {
  int idx = blockIdx.x * 256 + threadIdx.x;
  if (idx < total) {
    int i = idx >> 7;
    u[idx] = f2bf(inv_s[i] * x[idx]);
  }
}

// single kernel transposing W0 [128][256] and 3x Ws [256][256] to bf16
__global__ void transpose_all_kernel(const float* __restrict__ W0, const float* __restrict__ Ws,
                                     unsigned short* __restrict__ Wt0,
                                     unsigned short* __restrict__ WtS) {
  const int FH = 128 * 256, HH = 256 * 256;
  int idx = blockIdx.x * 256 + threadIdx.x;
  if (idx < FH) {
    int k = idx >> 8, n = idx & 255;
    Wt0[n * 128 + k] = f2bf(W0[idx]);
  } else {
    int t = idx - FH;
    if (t < 3 * HH) {
      int l = t >> 16;
      int rem = t & 65535;
      int k = rem >> 8, n = rem & 255;
      WtS[l * HH + n * 256 + k] = f2bf(Ws[t]);
    }
  }
}

// ----------------------------- aggregate ------------------------------------
// out_i = bf16( s_i * ( u_i + sum_{j in in(i)} u_j ) )
// One wave per node; LPR lanes (16B each) per row; EPW edge-groups per wave.
// At the 8xXCD L2-duplication fetch floor (round-4/5/6 all 3.7 TB/s).
template <int CH>
__global__ __launch_bounds__(256) void aggregate_kernel(
    const unsigned short* __restrict__ u, const int* __restrict__ row_off,
    const int* __restrict__ col, const float* __restrict__ inv_s,
    unsigned short* __restrict__ out, int N) {
  constexpr int LPR = CH / 8;    // lanes per row (each lane: 8 bf16 = 16B)
  constexpr int EPW = 64 / LPR;  // edge-groups in parallel per wave
  int wave = threadIdx.x >> 6;
  int lane = threadIdx.x & 63;
  int i = blockIdx.x * 4 + wave;
  if (i >= N) return;
  int sub = lane / LPR;
  int c = lane % LPR;
  int e0 = row_off[i], e1 = row_off[i + 1];
  int last = e1 - 1;
  const char* u8 = (const char*)u;
  float acc[8] = {};
  for (int e = e0 + sub; e < e1; e += 8 * EPW) {
    unsigned off[8];
    unsigned msk[8];
#pragma unroll
    for (int q = 0; q < 8; ++q) {
      int ee = e + q * EPW;
      bool v = ee < e1;
      int j = col[v ? ee : last];
      off[q] = (unsigned)j * (CH * 2) + c * 16;
      msk[q] = v ? 0xffffffffu : 0u;
    }
    u32x4 r[8];
#pragma unroll
    for (int q = 0; q < 8; ++q)
      asm volatile("global_load_dwordx4 %0, %1, %2"
                   : "=&v"(r[q])
                   : "v"(off[q]), "s"(u8));
    asm volatile("s_waitcnt vmcnt(0)" ::: "memory");
    __builtin_amdgcn_sched_barrier(0);  // rule #18: fence before register uses
#pragma unroll
    for (int q = 0; q < 8; ++q) acc8m(acc, r[q], msk[q]);
  }
#pragma unroll
  for (int k = 0; k < 8; ++k) {
    acc[k] += __shfl_down(acc[k], 32);
    if (EPW == 4) acc[k] += __shfl_down(acc[k], 16);
  }
  if (lane < LPR) {
    uint4 self = *(const uint4*)&u[(size_t)i * CH + c * 8];
    acc8(acc, self);
    float s = inv_s[i];
    uint4 o;
    o.x = pack2(s * acc[0], s * acc[1]);
    o.y = pack2(s * acc[2], s * acc[3]);
    o.z = pack2(s * acc[4], s * acc[5]);
    o.w = pack2(s * acc[6], s * acc[7]);
    *(uint4*)&out[(size_t)i * CH + c * 8] = o;
  }
}

// ----------------------------- MFMA GEMM ------------------------------------
// C[M,256] = A[M,K] @ W[K,256] (+bias, opt relu) -- LDS-free direct-global.
// Block = 64 rows x 256 cols, 4 waves; wave w owns cols w*64..w*64+63.
// Fragments load straight from global (A rows contiguous; Bt is 128KB,
// L2-resident and shared by all blocks). No barriers; k-loop fully unrolled
// so the compiler overlaps next-step loads with current MFMAs.
// WRITE_U: out = bf16( inv_s[r] * (C + gh[batch[r]]) )   (next layer's u)
// else:    out = bf16( C )                               (final h)
template <int K, bool RELU, bool WRITE_U>
__global__ __launch_bounds__(256, 4) void gemm_kernel(
    const unsigned short* __restrict__ A,   // [M][K] bf16
    const unsigned short* __restrict__ Bt,  // [256][K] bf16 (W transposed)
    const float* __restrict__ bias,         // [256]
    const float* __restrict__ inv_s, const int* __restrict__ batch,
    const float* __restrict__ gh,           // [G][256]
    unsigned short* __restrict__ out,       // [M][256] bf16
    int M) {
  int tid = threadIdx.x;
  int wave = tid >> 6, lane = tid & 63;
  int quad = lane >> 4, l15 = lane & 15;
  int row0 = blockIdx.x * 64;
  f32x4 acc[4][4];
#pragma unroll
  for (int m = 0; m < 4; ++m)
#pragma unroll
    for (int n = 0; n < 4; ++n) acc[m][n] = (f32x4){0.f, 0.f, 0.f, 0.f};

  // per-lane base rows (clamped: OOB rows read row M-1, never stored)
  const unsigned short* arow[4];
#pragma unroll
  for (int m = 0; m < 4; ++m) {
    int gr = row0 + m * 16 + l15;
    if (gr > M - 1) gr = M - 1;
    arow[m] = A + (size_t)gr * K;
  }
  const unsigned short* brow[4];
#pragma unroll
  for (int n = 0; n < 4; ++n) brow[n] = Bt + (size_t)(wave * 64 + n * 16 + l15) * K;

#pragma unroll
  for (int k0 = 0; k0 < K; k0 += 32) {
    bf16x8 af[4], bfr[4];
#pragma unroll
    for (int m = 0; m < 4; ++m)
      af[m] = __builtin_bit_cast(bf16x8, *(const uint4*)&arow[m][k0 + quad * 8]);
#pragma unroll
    for (int n = 0; n < 4; ++n)
      bfr[n] = __builtin_bit_cast(bf16x8, *(const uint4*)&brow[n][k0 + quad * 8]);
#pragma unroll
    for (int m = 0; m < 4; ++m)
#pragma unroll
      for (int n = 0; n < 4; ++n)
        acc[m][n] = __builtin_amdgcn_mfma_f32_16x16x32_bf16(af[m], bfr[n], acc[m][n], 0, 0, 0);
  }

  // epilogue: C/D map col=lane&15, row=(lane>>4)*4+reg
#pragma unroll
  for (int m = 0; m < 4; ++m) {
#pragma unroll
    for (int r = 0; r < 4; ++r) {
      int gr = row0 + m * 16 + quad * 4 + r;
      if (gr >= M) continue;
      float sv = 1.0f;
      int bofs = 0;
      if (WRITE_U) {
        sv = inv_s[gr];
        bofs = batch[gr] * 256;
      }
#pragma unroll
      for (int n = 0; n < 4; ++n) {
        int cc = wave * 64 + n * 16 + l15;
        float v = acc[m][n][r] + bias[cc];
        if (RELU) v = fmaxf(v, 0.f);
        if (WRITE_U) v = sv * (v + gh[bofs + cc]);
        out[(size_t)gr * 256 + cc] = f2bf(v);
      }
    }
  }
}

// ----------------------------- pool + final ---------------------------------

__global__ void pool_kernel(const unsigned short* __restrict__ h, const int* __restrict__ batch,
                            float* __restrict__ gmsum, float* __restrict__ cnt, int N, int chunk) {
  int start = blockIdx.x * chunk;
  int end = min(start + chunk, N);
  if (start >= end) return;
  int c = threadIdx.x;
  int g = batch[start];
  float acc = 0.0f;
  int run = 0;
  for (int n = start; n < end; ++n) {
    int bg = batch[n];
    if (bg != g) {
      atomicAdd(&gmsum[g * 256 + c], acc);
      if (c == 0) atomicAdd(&cnt[g], (float)run);
      acc = 0.0f;
      run = 0;
      g = bg;
    }
    acc += bf2f(h[(size_t)n * 256 + c]);
    run++;
  }
  atomicAdd(&gmsum[g * 256 + c], acc);
  if (c == 0) atomicAdd(&cnt[g], (float)run);
}

__global__ void final_kernel(const float* __restrict__ gmsum, const float* __restrict__ cnt,
                             const float* __restrict__ gh, const float* __restrict__ Wlin,
                             const float* __restrict__ blin, float* __restrict__ y,
                             float* __restrict__ gm_out, int G) {
  int g = blockIdx.x;
  int c = threadIdx.x;
  __shared__ float row[256];
  float v = gmsum[g * 256 + c] / fmaxf(cnt[g], 1.0f) + gh[g * 256 + c];
  gm_out[g * 256 + c] = v;
  row[c] = v;
  __syncthreads();
  if (c < 10) {
    float acc = blin[c];
    for (int k = 0; k < 256; ++k) acc += row[k] * Wlin[k * 10 + c];
    y[g * 10 + c] = acc;
  }
}

// ----------------------------- launch ----------------------------------------

extern "C" void kernel_launch(void* const* d_in, const int* in_sizes, int n_in,
                              void* d_out, int out_size, void* d_ws, size_t ws_size,
                              hipStream_t stream) {
  const float* x = (const float*)d_in[0];
  const int* ei = (const int*)d_in[1];
  const int* batch = (const int*)d_in[2];
  const float* gh = (const float*)d_in[3];
  const float* W0 = (const float*)d_in[4];
  const float* b0 = (const float*)d_in[5];
  const float* Ws = (const float*)d_in[6];
  const float* bs = (const float*)d_in[7];
  const float* Wlin = (const float*)d_in[8];
  const float* blin = (const float*)d_in[9];
  float* out = (float*)d_out;

  const int N = in_sizes[2];
  const int E = in_sizes[1] / 2;
  const int G = in_sizes[3] / 256;
  const int H = 256, L = 3, C = 10, F = 128;

  char* ws = (char*)d_ws;
  size_t off = 0;
  auto alloc = [&](size_t bytes) {
    void* p = ws + off;
    off += (bytes + 255) & ~(size_t)255;
    return p;
  };
  // NOTE: deg+cursor and cnt+gmsum are kept contiguous for merged memsets.
  size_t degspan = ((size_t)N * 4 + 255) & ~(size_t)255;
  size_t cntspan = ((size_t)G * 4 + 255) & ~(size_t)255;
  int* deg = (int*)alloc((size_t)N * 4);
  int* cursor = (int*)alloc((size_t)N * 4);
  float* cnt = (float*)alloc((size_t)G * 4);
  float* gmsum = (float*)alloc((size_t)G * H * 4);
  int* row_off = (int*)alloc((size_t)(N + 1) * 4);
  int* bsum = (int*)alloc(256 * 4);
  int* boff = (int*)alloc(256 * 4);
  int* col = (int*)alloc((size_t)E * 4);
  float* inv_s = (float*)alloc((size_t)N * 4);
  unsigned short* u_x = (unsigned short*)alloc((size_t)N * F * 2);   // s*x
  unsigned short* uA = (unsigned short*)alloc((size_t)N * H * 2);    // s*(h+res)
  unsigned short* aggA = (unsigned short*)alloc((size_t)N * H * 2);  // aggregate out / GEMM A
  unsigned short* hfin = (unsigned short*)alloc((size_t)N * H * 2);  // final h
  unsigned short* Wt0 = (unsigned short*)alloc((size_t)F * H * 2);   // [256][128]
  unsigned short* WtS = (unsigned short*)alloc((size_t)L * H * H * 2);

  const int* srcv = ei;
  const int* dstv = ei + E;

  hipMemsetAsync(deg, 0, degspan + (size_t)N * 4, stream);       // deg + cursor
  hipMemsetAsync(cnt, 0, cntspan + (size_t)G * H * 4, stream);   // cnt + gmsum

  int EB = (E + 255) / 256;
  int NB = (N + 255) / 256;
  count_deg_kernel<<<EB, 256, 0, stream>>>(dstv, deg, E);
  scan_partial_kernel<<<NB, 256, 0, stream>>>(deg, inv_s, bsum, N);
  scan_block_kernel<<<1, 256, 0, stream>>>(bsum, boff, row_off, NB, N);
  scan_final_kernel<<<NB, 256, 0, stream>>>(deg, boff, row_off, N);
  fill_csr_kernel<<<EB, 256, 0, stream>>>(srcv, dstv, row_off, cursor, col, E);

  prep_ux_kernel<<<(N * F + 255) / 256, 256, 0, stream>>>(x, inv_s, u_x, N * F);
  int TW = F * H + 3 * H * H;
  transpose_all_kernel<<<(TW + 255) / 256, 256, 0, stream>>>(W0, Ws, Wt0, WtS);

  int AGG_GRID = (N + 3) / 4;
  int GEMM_GRID = (N + 63) / 64;

  // layer 0: agg(u_x) -> GEMM K=128 (no relu) -> uA = s*(h0+res)
  aggregate_kernel<128><<<AGG_GRID, 256, 0, stream>>>(u_x, row_off, col, inv_s, aggA, N);
  gemm_kernel<128, false, true><<<GEMM_GRID, 256, 0, stream>>>(aggA, Wt0, b0, inv_s, batch, gh,
                                                               uA, N);
  // layers 1..2: agg(uA) -> GEMM relu -> uA
  for (int l = 0; l < 2; ++l) {
    aggregate_kernel<256><<<AGG_GRID, 256, 0, stream>>>(uA, row_off, col, inv_s, aggA, N);
    gemm_kernel<256, true, true><<<GEMM_GRID, 256, 0, stream>>>(
        aggA, WtS + (size_t)l * H * H, bs + (size_t)l * H, inv_s, batch, gh, uA, N);
  }
  // layer 3: agg(uA) -> GEMM relu -> h (bf16)
  aggregate_kernel<256><<<AGG_GRID, 256, 0, stream>>>(uA, row_off, col, inv_s, aggA, N);
  gemm_kernel<256, true, false><<<GEMM_GRID, 256, 0, stream>>>(
      aggA, WtS + (size_t)2 * H * H, bs + (size_t)2 * H, inv_s, batch, gh, hfin, N);

  int PB = 1024;
  int chunk = (N + PB - 1) / PB;
  pool_kernel<<<PB, 256, 0, stream>>>(hfin, batch, gmsum, cnt, N, chunk);
  final_kernel<<<G, 256, 0, stream>>>(gmsum, cnt, gh, Wlin, blin, out, out + (size_t)G * C, G);
}